// Round 1
// baseline (397.634 us; speedup 1.0000x reference)
//
#include <hip/hip_runtime.h>
#include <stdint.h>

#define BATCH 256
#define M 512
#define N 512
#define K 128

typedef int int4v __attribute__((ext_vector_type(4)));
typedef float float4v __attribute__((ext_vector_type(4)));

// One block per batch (grid=256, 1 block/CU). 512 threads = 8 waves.
// Inputs arrive as INT32 (harness widens integer dtypes).
// Stage: read a[b], b[b] int32 coalesced, pack low bytes -> int8 in
// XOR-swizzled LDS (64KB + 64KB). Compute: wave w owns the 512x64 output
// strip at columns w*64, iterating 8 row-supertiles of 64x64 with
// mfma_i32_16x16x64_i8 (K=128 -> 2 k-steps), B-fragments hoisted.
//
// R1 change vs previous best (361 us): operand-SWAPPED MFMA epilogue.
// mfma(bf, af) computes the transposed 16x16 tile, so C/D layout
// (col=lane&15, row=quad*4+reg) maps col->m, regs->4 consecutive n.
// Each lane stores one float4 (dwordx4, nontemporal) per (i,j) pair
// directly from its 4 acc regs: 4x fewer store insts, no acc[4][4]
// array (peak VGPR pressure -~60, removes spill risk at the 256-reg
// launch_bounds cap).
__global__ __launch_bounds__(512, 2) void bmm_s8s8_f32_kernel(
    const int* __restrict__ A32,       // [BATCH, M, K] int32 (values in [-128,127])
    const int* __restrict__ B32,       // [BATCH, N, K] int32
    const float* __restrict__ alpha_p, // scalar
    float* __restrict__ O)             // [BATCH, M, N] fp32
{
    __shared__ int8_t As[M * K]; // 64 KB
    __shared__ int8_t Bs[N * K]; // 64 KB

    const int tid = threadIdx.x;
    const int bat = blockIdx.x;

    const int* Ag = A32 + (size_t)bat * (M * K);
    const int* Bg = B32 + (size_t)bat * (N * K);

    // ---- Stage + pack: 16384 dword-groups per matrix, 512 threads x 32 iters.
    // LDS layout: row-major [row][128] int8 with 16B-chunk XOR swizzle:
    //   byte addr = row*128 + (chunk ^ (row & 7))*16 + sub*4
#pragma unroll 4
    for (int i = 0; i < 32; ++i) {
        const int g   = i * 512 + tid;   // dword-group 0..16383
        const int row = g >> 5;          // 32 groups per 128-int32 row
        const int kg  = g & 31;
        const int kc  = kg >> 2;         // 16B chunk 0..7
        const int sub = kg & 3;
        const int kcs = kc ^ (row & 7);

        int4v wa = *(const int4v*)(Ag + (size_t)g * 4);
        int4v wb = *(const int4v*)(Bg + (size_t)g * 4);
        const int pa = (wa.x & 0xff) | ((wa.y & 0xff) << 8) |
                       ((wa.z & 0xff) << 16) | (wa.w << 24);
        const int pb = (wb.x & 0xff) | ((wb.y & 0xff) << 8) |
                       ((wb.z & 0xff) << 16) | (wb.w << 24);
        *(int*)(As + row * 128 + kcs * 16 + sub * 4) = pa;
        *(int*)(Bs + row * 128 + kcs * 16 + sub * 4) = pb;
    }
    __syncthreads();

    const int lane = tid & 63;
    const int wave = tid >> 6;
    const int l15  = lane & 15;
    const int quad = lane >> 4;
    const int sn   = wave; // supertile column (n-offset sn*64)

    // Hoist B fragments for this wave's column strip.
    // Operand layout: lane holds row (l15-indexed) x 16B k-chunk (quad);
    // exact slot->k bijection cancels between the two fragments (both
    // operands use the identical load scheme, so the swap is safe).
    int4v bf[2][4];
#pragma unroll
    for (int ks = 0; ks < 2; ++ks)
#pragma unroll
        for (int j = 0; j < 4; ++j) {
            const int rb = sn * 64 + j * 16 + l15;
            const int kc = (ks * 4 + quad) ^ (rb & 7);
            bf[ks][j] = *(const int4v*)(Bs + rb * 128 + kc * 16);
        }

    const float alpha = *alpha_p;

    for (int sm = 0; sm < 8; ++sm) {
        int4v af[2][4];
#pragma unroll
        for (int ks = 0; ks < 2; ++ks)
#pragma unroll
            for (int i = 0; i < 4; ++i) {
                const int ra = sm * 64 + i * 16 + l15;
                const int kc = (ks * 4 + quad) ^ (ra & 7);
                af[ks][i] = *(const int4v*)(As + ra * 128 + kc * 16);
            }

        // Swapped-operand MFMA: D = bf x af -> within-tile col (lane&15) = m,
        // row (quad*4 + reg) = n. Lane's 4 acc regs are 4 consecutive n.
        //   m_global = sm*64 + i*16 + l15
        //   n_global = sn*64 + j*16 + quad*4 + reg
        float* Obase = O + ((size_t)bat * M + sm * 64 + l15) * N + sn * 64 + quad * 4;
#pragma unroll
        for (int i = 0; i < 4; ++i) {
#pragma unroll
            for (int j = 0; j < 4; ++j) {
                int4v acc = (int4v){0, 0, 0, 0};
#pragma unroll
                for (int ks = 0; ks < 2; ++ks)
                    acc = __builtin_amdgcn_mfma_i32_16x16x64_i8(
                        bf[ks][j], af[ks][i], acc, 0, 0, 0);
                float4v v;
                v.x = alpha * (float)acc.x;
                v.y = alpha * (float)acc.y;
                v.z = alpha * (float)acc.z;
                v.w = alpha * (float)acc.w;
                __builtin_nontemporal_store(
                    v, (float4v*)(Obase + (size_t)(i * 16) * N + j * 16));
            }
        }
    }
}

extern "C" void kernel_launch(void* const* d_in, const int* in_sizes, int n_in,
                              void* d_out, int out_size, void* d_ws, size_t ws_size,
                              hipStream_t stream) {
    const int*   a     = (const int*)d_in[0];
    const int*   b     = (const int*)d_in[1];
    const float* alpha = (const float*)d_in[2];
    float*       out   = (float*)d_out;

    dim3 grid(BATCH);
    dim3 block(512);
    bmm_s8s8_f32_kernel<<<grid, block, 0, stream>>>(a, b, alpha, out);
}

// Round 2
// 379.375 us; speedup vs baseline: 1.0481x; 1.0481x over previous
//
#include <hip/hip_runtime.h>
#include <stdint.h>

#define BATCH 256
#define M 512
#define N 512
#define K 128

// R2: 256x256 output tiles, 4 blocks/batch, grid=1024, LDS 64KB/block,
// launch_bounds(512,4) (VGPR cap 128) -> 2 blocks/CU resident. Rationale:
// previous 1-block/CU structure had zero overlap between the latency-bound
// staging phase and compute/store phases. Epilogue reverted to R0's scalar
// dword stores (4 dense 64B segments/inst) after R1's dwordx4-scatter
// regression.

typedef int int4v __attribute__((ext_vector_type(4)));

__global__ __launch_bounds__(512, 4) void bmm_s8s8_f32_kernel(
    const int* __restrict__ A32,       // [BATCH, M, K] int32 (values in [-128,127])
    const int* __restrict__ B32,       // [BATCH, N, K] int32
    const float* __restrict__ alpha_p, // scalar
    float* __restrict__ O)             // [BATCH, M, N] fp32
{
    __shared__ int8_t As[256 * K]; // 32 KB (m-tile)
    __shared__ int8_t Bs[256 * K]; // 32 KB (n-tile)

    const int tid = threadIdx.x;

    // Bijective XCD swizzle (grid=1024, 8 XCDs, 128 blocks each): the 4 tiles
    // of one batch (sharing A/B halves) land on the same XCD's L2.
    const int bid  = (int)blockIdx.x;
    const int vbid = (bid & 7) * 128 + (bid >> 3);
    const int bat  = vbid >> 2;
    const int mt   = (vbid >> 1) & 1; // m-tile 0/1
    const int nt   = vbid & 1;        // n-tile 0/1

    const int* Ag = A32 + (size_t)bat * (M * K) + (size_t)mt * 256 * K;
    const int* Bg = B32 + (size_t)bat * (N * K) + (size_t)nt * 256 * K;

    // ---- Stage + pack: 8192 dword-groups per matrix, 512 threads x 16 iters,
    // batched 4 iters deep (8 x 16B loads in flight per thread) for latency.
    // LDS layout: row-major [row][128] int8 with 16B-chunk XOR swizzle:
    //   byte addr = row*128 + (chunk ^ (row & 7))*16 + sub*4
#pragma unroll
    for (int ob = 0; ob < 4; ++ob) {
        int4v wa[4], wb[4];
#pragma unroll
        for (int u = 0; u < 4; ++u) {
            const int g = (ob * 4 + u) * 512 + tid; // dword-group 0..8191
            wa[u] = *(const int4v*)(Ag + (size_t)g * 4);
            wb[u] = *(const int4v*)(Bg + (size_t)g * 4);
        }
#pragma unroll
        for (int u = 0; u < 4; ++u) {
            const int g   = (ob * 4 + u) * 512 + tid;
            const int row = g >> 5;          // 32 groups per 128-int32 row
            const int kg  = g & 31;
            const int kc  = kg >> 2;         // 16B chunk 0..7
            const int sub = kg & 3;
            const int kcs = kc ^ (row & 7);
            const int pa = (wa[u].x & 0xff) | ((wa[u].y & 0xff) << 8) |
                           ((wa[u].z & 0xff) << 16) | (wa[u].w << 24);
            const int pb = (wb[u].x & 0xff) | ((wb[u].y & 0xff) << 8) |
                           ((wb[u].z & 0xff) << 16) | (wb[u].w << 24);
            *(int*)(As + row * 128 + kcs * 16 + sub * 4) = pa;
            *(int*)(Bs + row * 128 + kcs * 16 + sub * 4) = pb;
        }
    }
    __syncthreads();

    const int lane = tid & 63;
    const int wave = tid >> 6;
    const int l15  = lane & 15;
    const int quad = lane >> 4;

    // Wave w owns the 256x32 column strip at n-offset w*32 within the tile.
    // Hoist B fragments: lane holds row (l15) x 16B k-chunk (quad); the
    // swizzle slot->k bijection cancels between A and B fragments.
    int4v bf[2][2];
#pragma unroll
    for (int ks = 0; ks < 2; ++ks)
#pragma unroll
        for (int j = 0; j < 2; ++j) {
            const int rb = wave * 32 + j * 16 + l15;
            const int kc = (ks * 4 + quad) ^ (rb & 7);
            bf[ks][j] = *(const int4v*)(Bs + rb * 128 + kc * 16);
        }

    const float alpha = *alpha_p;

    for (int sm = 0; sm < 4; ++sm) {
        int4v af[2][4];
#pragma unroll
        for (int ks = 0; ks < 2; ++ks)
#pragma unroll
            for (int i = 0; i < 4; ++i) {
                const int ra = sm * 64 + i * 16 + l15;
                const int kc = (ks * 4 + quad) ^ (ra & 7);
                af[ks][i] = *(const int4v*)(As + ra * 128 + kc * 16);
            }

        int4v acc[4][2];
#pragma unroll
        for (int i = 0; i < 4; ++i)
#pragma unroll
            for (int j = 0; j < 2; ++j)
                acc[i][j] = (int4v){0, 0, 0, 0};

#pragma unroll
        for (int ks = 0; ks < 2; ++ks)
#pragma unroll
            for (int i = 0; i < 4; ++i)
#pragma unroll
                for (int j = 0; j < 2; ++j)
                    acc[i][j] = __builtin_amdgcn_mfma_i32_16x16x64_i8(
                        af[ks][i], bf[ks][j], acc[i][j], 0, 0, 0);

        // C/D layout: col = lane&15 (n), row = quad*4 + reg (m).
        float* Ob = O + ((size_t)bat * M + mt * 256 + sm * 64 + quad * 4) * N +
                    nt * 256 + wave * 32 + l15;
#pragma unroll
        for (int i = 0; i < 4; ++i)
#pragma unroll
            for (int r = 0; r < 4; ++r) {
                float* rowp = Ob + (size_t)(i * 16 + r) * N;
#pragma unroll
                for (int j = 0; j < 2; ++j)
                    rowp[j * 16] = alpha * (float)acc[i][j][r];
            }
    }
}

extern "C" void kernel_launch(void* const* d_in, const int* in_sizes, int n_in,
                              void* d_out, int out_size, void* d_ws, size_t ws_size,
                              hipStream_t stream) {
    const int*   a     = (const int*)d_in[0];
    const int*   b     = (const int*)d_in[1];
    const float* alpha = (const float*)d_in[2];
    float*       out   = (float*)d_out;

    dim3 grid(BATCH * 4);
    dim3 block(512);
    bmm_s8s8_f32_kernel<<<grid, block, 0, stream>>>(a, b, alpha, out);
}

// Round 3
// 361.832 us; speedup vs baseline: 1.0989x; 1.0485x over previous
//
#include <hip/hip_runtime.h>
#include <stdint.h>

#define BATCH 256
#define M 512
#define N 512
#define K 128

typedef int int4v __attribute__((ext_vector_type(4)));
typedef float float4v __attribute__((ext_vector_type(4)));

// R3 = R0 (best, 361us) with ONE change: epilogue goes through a per-wave
// 4KB LDS transpose so every global store inst writes 4 rows x 256B
// CONTIGUOUS (each 128B line completed by a single inst -> no partial-line
// RMW exposure in TCC), 16 store insts per supertile instead of 64.
// Stage/pack, XOR-swizzled operand LDS, bf hoist, MFMA loop: identical to R0.
__global__ __launch_bounds__(512, 2) void bmm_s8s8_f32_kernel(
    const int* __restrict__ A32,       // [BATCH, M, K] int32 (values in [-128,127])
    const int* __restrict__ B32,       // [BATCH, N, K] int32
    const float* __restrict__ alpha_p, // scalar
    float* __restrict__ O)             // [BATCH, M, N] fp32
{
    __shared__ int8_t As[M * K];       // 64 KB
    __shared__ int8_t Bs[N * K];       // 64 KB
    __shared__ float  Scr[8][1024];    // 32 KB: per-wave 16x64 f32 store-transpose

    const int tid = threadIdx.x;
    const int bat = blockIdx.x;

    const int* Ag = A32 + (size_t)bat * (M * K);
    const int* Bg = B32 + (size_t)bat * (N * K);

    // ---- Stage + pack (identical to R0): 16384 dword-groups per matrix.
    // LDS layout: row-major [row][128] int8 with 16B-chunk XOR swizzle:
    //   byte addr = row*128 + (chunk ^ (row & 7))*16 + sub*4
#pragma unroll 4
    for (int i = 0; i < 32; ++i) {
        const int g   = i * 512 + tid;   // dword-group 0..16383
        const int row = g >> 5;          // 32 groups per 128-int32 row
        const int kg  = g & 31;
        const int kc  = kg >> 2;         // 16B chunk 0..7
        const int sub = kg & 3;
        const int kcs = kc ^ (row & 7);

        int4v wa = *(const int4v*)(Ag + (size_t)g * 4);
        int4v wb = *(const int4v*)(Bg + (size_t)g * 4);
        const int pa = (wa.x & 0xff) | ((wa.y & 0xff) << 8) |
                       ((wa.z & 0xff) << 16) | (wa.w << 24);
        const int pb = (wb.x & 0xff) | ((wb.y & 0xff) << 8) |
                       ((wb.z & 0xff) << 16) | (wb.w << 24);
        *(int*)(As + row * 128 + kcs * 16 + sub * 4) = pa;
        *(int*)(Bs + row * 128 + kcs * 16 + sub * 4) = pb;
    }
    __syncthreads();

    const int lane = tid & 63;
    const int wave = tid >> 6;
    const int l15  = lane & 15;
    const int quad = lane >> 4;
    const int sn   = wave; // supertile column (n-offset sn*64)

    // Hoist B fragments for this wave's column strip (identical to R0).
    int4v bf[2][4];
#pragma unroll
    for (int ks = 0; ks < 2; ++ks)
#pragma unroll
        for (int j = 0; j < 4; ++j) {
            const int rb = sn * 64 + j * 16 + l15;
            const int kc = (ks * 4 + quad) ^ (rb & 7);
            bf[ks][j] = *(const int4v*)(Bs + rb * 128 + kc * 16);
        }

    const float alpha = *alpha_p;

    for (int sm = 0; sm < 8; ++sm) {
        int4v af[2][4];
#pragma unroll
        for (int ks = 0; ks < 2; ++ks)
#pragma unroll
            for (int i = 0; i < 4; ++i) {
                const int ra = sm * 64 + i * 16 + l15;
                const int kc = (ks * 4 + quad) ^ (ra & 7);
                af[ks][i] = *(const int4v*)(As + ra * 128 + kc * 16);
            }

        int4v acc[4][4];
#pragma unroll
        for (int i = 0; i < 4; ++i)
#pragma unroll
            for (int j = 0; j < 4; ++j)
                acc[i][j] = (int4v){0, 0, 0, 0};

#pragma unroll
        for (int ks = 0; ks < 2; ++ks)
#pragma unroll
            for (int i = 0; i < 4; ++i)
#pragma unroll
                for (int j = 0; j < 4; ++j)
                    acc[i][j] = __builtin_amdgcn_mfma_i32_16x16x64_i8(
                        af[ks][i], bf[ks][j], acc[i][j], 0, 0, 0);

        // ---- Epilogue: per 16-row i-block, transpose through wave-private
        // LDS scratch so stores are full-line contiguous.
        // Scratch addressing: addr(m, n) = m*64 + (n ^ (((m>>2)&1)<<4)).
        //   Write inst (fixed r,j; lanes quad x l15): 2 lanes/bank, even. Free.
        //   Read inst (b128, fixed r2): every bank hit 8x, even = BW floor.
#pragma unroll
        for (int i = 0; i < 4; ++i) {
            const int wkey = (quad & 1) << 4; // ((m>>2)&1)<<4 with m = quad*4+r
#pragma unroll
            for (int r = 0; r < 4; ++r) {
                const int m = quad * 4 + r;
#pragma unroll
                for (int j = 0; j < 4; ++j) {
                    const int n = j * 16 + l15;
                    Scr[wave][m * 64 + (n ^ wkey)] = alpha * (float)acc[i][j][r];
                }
            }
            asm volatile("s_waitcnt lgkmcnt(0)" ::: "memory");
            __builtin_amdgcn_sched_barrier(0);
#pragma unroll
            for (int r2 = 0; r2 < 4; ++r2) {
                const int m    = r2 * 4 + quad;
                const int rkey = (r2 & 1) << 4; // ((m>>2)&1)<<4
                const float4v v =
                    *(const float4v*)&Scr[wave][m * 64 + ((l15 * 4) ^ rkey)];
                float* p = O + ((size_t)bat * M + sm * 64 + i * 16 + m) * N +
                           sn * 64 + l15 * 4;
                *(float4v*)p = v;
            }
            // WAR (next i overwrites scratch) is safe: DS pipe is in-order
            // per wave; compiler preserves order on may-alias LDS accesses.
        }
    }
}

extern "C" void kernel_launch(void* const* d_in, const int* in_sizes, int n_in,
                              void* d_out, int out_size, void* d_ws, size_t ws_size,
                              hipStream_t stream) {
    const int*   a     = (const int*)d_in[0];
    const int*   b     = (const int*)d_in[1];
    const float* alpha = (const float*)d_in[2];
    float*       out   = (float*)d_out;

    dim3 grid(BATCH);
    dim3 block(512);
    bmm_s8s8_f32_kernel<<<grid, block, 0, stream>>>(a, b, alpha, out);
}

// Round 4
// 360.434 us; speedup vs baseline: 1.1032x; 1.0039x over previous
//
#include <hip/hip_runtime.h>
#include <stdint.h>

#define BATCH 256
#define M 512
#define N 512
#define K 128

typedef int int4v __attribute__((ext_vector_type(4)));

// R4 = R0 structure with A-staging software-pipelined across supertiles.
// Stage B (64KB) + A-supertile-0 up front; in the main loop, supertile sm's
// compute+store overlaps the global loads of A-supertile sm+1 (issued at the
// top of the iter, packed+written to LDS at the bottom). Per-sm raw s_barrier
// waits lgkmcnt(0) ONLY -- global stores stay in flight across barriers
// (no vmcnt(0) drain). Zero extra HBM traffic vs R0. Epilogue = R0's proven
// scalar-store form (R3 showed store pattern at equal bytes is neutral).
__global__ __launch_bounds__(512, 2) void bmm_s8s8_f32_kernel(
    const int* __restrict__ A32,       // [BATCH, M, K] int32 (values in [-128,127])
    const int* __restrict__ B32,       // [BATCH, N, K] int32
    const float* __restrict__ alpha_p, // scalar
    float* __restrict__ O)             // [BATCH, M, N] fp32
{
    __shared__ int8_t As[M * K]; // 64 KB
    __shared__ int8_t Bs[N * K]; // 64 KB

    const int tid = threadIdx.x;
    const int bat = blockIdx.x;

    const int* Ag = A32 + (size_t)bat * (M * K);
    const int* Bg = B32 + (size_t)bat * (N * K);

    // LDS layout (both matrices): row-major [row][128] int8, 16B-chunk XOR
    // swizzle: byte addr = row*128 + (chunk ^ (row & 7))*16 + sub*4

    // ---- Issue A-supertile-0 loads early (complete under the B stage).
    // A-chunk for supertile s = dword-groups [s*2048, s*2048+2048): 4/thread.
    int4v a0[4];
#pragma unroll
    for (int u = 0; u < 4; ++u) {
        const int g = u * 512 + tid;
        a0[u] = *(const int4v*)(Ag + (size_t)g * 4);
    }

    // ---- Stage B fully: 16384 dword-groups, 512 threads x 32 iters.
#pragma unroll 4
    for (int i = 0; i < 32; ++i) {
        const int g   = i * 512 + tid;
        const int row = g >> 5;
        const int kg  = g & 31;
        const int kc  = kg >> 2;
        const int sub = kg & 3;
        const int kcs = kc ^ (row & 7);
        int4v wb = *(const int4v*)(Bg + (size_t)g * 4);
        const int pb = (wb.x & 0xff) | ((wb.y & 0xff) << 8) |
                       ((wb.z & 0xff) << 16) | (wb.w << 24);
        *(int*)(Bs + row * 128 + kcs * 16 + sub * 4) = pb;
    }

    // ---- Pack + write A-supertile-0.
#pragma unroll
    for (int u = 0; u < 4; ++u) {
        const int g   = u * 512 + tid;
        const int row = g >> 5;
        const int kg  = g & 31;
        const int kc  = kg >> 2;
        const int sub = kg & 3;
        const int kcs = kc ^ (row & 7);
        const int pa = (a0[u].x & 0xff) | ((a0[u].y & 0xff) << 8) |
                       ((a0[u].z & 0xff) << 16) | (a0[u].w << 24);
        *(int*)(As + row * 128 + kcs * 16 + sub * 4) = pa;
    }
    __syncthreads();

    const int lane = tid & 63;
    const int wave = tid >> 6;
    const int l15  = lane & 15;
    const int quad = lane >> 4;
    const int sn   = wave; // supertile column (n-offset sn*64)

    // Hoist B fragments for this wave's column strip (identical to R0).
    int4v bf[2][4];
#pragma unroll
    for (int ks = 0; ks < 2; ++ks)
#pragma unroll
        for (int j = 0; j < 4; ++j) {
            const int rb = sn * 64 + j * 16 + l15;
            const int kc = (ks * 4 + quad) ^ (rb & 7);
            bf[ks][j] = *(const int4v*)(Bs + rb * 128 + kc * 16);
        }

    const float alpha = *alpha_p;

    for (int sm = 0; sm < 8; ++sm) {
        // Issue next A-chunk's global loads; they complete under MFMA+stores.
        int4v pre[4];
        if (sm < 7) {
#pragma unroll
            for (int u = 0; u < 4; ++u) {
                const int g = (sm + 1) * 2048 + u * 512 + tid;
                pre[u] = *(const int4v*)(Ag + (size_t)g * 4);
            }
        }

        int4v af[2][4];
#pragma unroll
        for (int ks = 0; ks < 2; ++ks)
#pragma unroll
            for (int i = 0; i < 4; ++i) {
                const int ra = sm * 64 + i * 16 + l15;
                const int kc = (ks * 4 + quad) ^ (ra & 7);
                af[ks][i] = *(const int4v*)(As + ra * 128 + kc * 16);
            }

        int4v acc[4][4];
#pragma unroll
        for (int i = 0; i < 4; ++i)
#pragma unroll
            for (int j = 0; j < 4; ++j)
                acc[i][j] = (int4v){0, 0, 0, 0};

#pragma unroll
        for (int ks = 0; ks < 2; ++ks)
#pragma unroll
            for (int i = 0; i < 4; ++i)
#pragma unroll
                for (int j = 0; j < 4; ++j)
                    acc[i][j] = __builtin_amdgcn_mfma_i32_16x16x64_i8(
                        af[ks][i], bf[ks][j], acc[i][j], 0, 0, 0);

        // C/D layout: col = lane&15 (n), row = quad*4 + reg (m).
        float* Ob = O + ((size_t)bat * M + sm * 64 + quad * 4) * N + sn * 64 + l15;
#pragma unroll
        for (int i = 0; i < 4; ++i)
#pragma unroll
            for (int r = 0; r < 4; ++r) {
                float* rowp = Ob + (size_t)(i * 16 + r) * N;
#pragma unroll
                for (int j = 0; j < 4; ++j)
                    rowp[j * 16] = alpha * (float)acc[i][j][r];
            }

        if (sm < 7) {
            // Pack + write A-chunk sm+1. Safe vs other waves: the per-sm
            // barrier keeps all waves in the same interval; reads touch
            // As[sm], these writes touch As[sm+1] (disjoint).
#pragma unroll
            for (int u = 0; u < 4; ++u) {
                const int g   = (sm + 1) * 2048 + u * 512 + tid;
                const int row = g >> 5;
                const int kg  = g & 31;
                const int kc  = kg >> 2;
                const int sub = kg & 3;
                const int kcs = kc ^ (row & 7);
                const int pa = (pre[u].x & 0xff) | ((pre[u].y & 0xff) << 8) |
                               ((pre[u].z & 0xff) << 16) | (pre[u].w << 24);
                *(int*)(As + row * 128 + kcs * 16 + sub * 4) = pa;
            }
            // Raw barrier: drain LDS ops only; global stores stay in flight.
            asm volatile("s_waitcnt lgkmcnt(0)" ::: "memory");
            __builtin_amdgcn_s_barrier();
            __builtin_amdgcn_sched_barrier(0);
        }
    }
}

extern "C" void kernel_launch(void* const* d_in, const int* in_sizes, int n_in,
                              void* d_out, int out_size, void* d_ws, size_t ws_size,
                              hipStream_t stream) {
    const int*   a     = (const int*)d_in[0];
    const int*   b     = (const int*)d_in[1];
    const float* alpha = (const float*)d_in[2];
    float*       out   = (float*)d_out;

    dim3 grid(BATCH);
    dim3 block(512);
    bmm_s8s8_f32_kernel<<<grid, block, 0, stream>>>(a, b, alpha, out);
}